// Round 1
// baseline (147.293 us; speedup 1.0000x reference)
//
#include <hip/hip_runtime.h>

// Problem: x [64, 512, 512, 3] f32.  out = clip((mean_c(x) - q10)/max(q90-q10, .01), 0, 1)
// B=64, HW=262144 pixels/batch, 786432 floats/batch.

#define BINS 8192
#define PIX_PER_BATCH 262144
#define FLT_PER_BATCH 786432

// ---------------- K1: fused channel-mean + per-block histogram ----------------
// Each block handles one contiguous chunk of `chunk` pixels of one batch.
// Writes xm to out (float4 coalesced), and a private u16 histogram to ws.
__global__ __launch_bounds__(256) void k_mean_hist(const float* __restrict__ x,
                                                   float* __restrict__ xm,
                                                   unsigned short* __restrict__ subhist,
                                                   int nb, int chunk) {
    __shared__ unsigned int hist[BINS];
    const int tid = threadIdx.x;
    const int b = blockIdx.x / nb;
    const int c = blockIdx.x % nb;

    for (int i = tid; i < BINS; i += 256) hist[i] = 0;
    __syncthreads();

    const float4* __restrict__ X4 = (const float4*)x;
    float4* __restrict__ O4 = (float4*)xm;

    const int pix0 = b * PIX_PER_BATCH + c * chunk;   // multiple of 1024
    const int iters = chunk / 1024;                   // 256 threads x 4 pixels

    for (int it = 0; it < iters; ++it) {
        const int p = pix0 + it * 1024 + tid * 4;     // pixel index, %4==0
        const int f4 = (p * 3) >> 2;                  // float4 index (p*3 %4==0)
        float4 a = X4[f4 + 0];
        float4 d = X4[f4 + 1];
        float4 e = X4[f4 + 2];
        const float k3 = 1.0f / 3.0f;
        float s0 = (a.x + a.y + a.z) * k3;
        float s1 = (a.w + d.x + d.y) * k3;
        float s2 = (d.z + d.w + e.x) * k3;
        float s3 = (e.y + e.z + e.w) * k3;
        O4[p >> 2] = make_float4(s0, s1, s2, s3);
        int b0 = min(BINS - 1, max(0, (int)(s0 * (float)BINS)));
        int b1 = min(BINS - 1, max(0, (int)(s1 * (float)BINS)));
        int b2 = min(BINS - 1, max(0, (int)(s2 * (float)BINS)));
        int b3 = min(BINS - 1, max(0, (int)(s3 * (float)BINS)));
        atomicAdd(&hist[b0], 1u);
        atomicAdd(&hist[b1], 1u);
        atomicAdd(&hist[b2], 1u);
        atomicAdd(&hist[b3], 1u);
    }
    __syncthreads();

    unsigned short* dst = subhist + (size_t)(b * nb + c) * BINS;
    for (int i = tid; i < BINS; i += 256) {
        unsigned int v = hist[i];
        dst[i] = (unsigned short)(v > 65535u ? 65535u : v);
    }
}

// ---------------- K2: per-batch quantiles from histogram ----------------
// One block per batch. Sum nb sub-hists, exclusive scan, find the bins holding
// order statistics {26214, 26215, 235928, 235929} (q*(n-1) linear interp,
// n=262144), estimate value within bin assuming uniform spread.
__global__ __launch_bounds__(256) void k_quantile(const unsigned short* __restrict__ subhist,
                                                  float* __restrict__ lo_inv,
                                                  int nb) {
    __shared__ unsigned int hist[BINS];
    __shared__ unsigned int tsum[256];
    __shared__ float vals[4];
    const int b = blockIdx.x;
    const int tid = threadIdx.x;

    for (int i = tid; i < BINS; i += 256) {
        unsigned int acc = 0;
        for (int c = 0; c < nb; ++c)
            acc += subhist[(size_t)(b * nb + c) * BINS + i];
        hist[i] = acc;
    }
    __syncthreads();

    // strip sums: thread t owns bins [t*32, t*32+32)
    const int base = tid * 32;
    unsigned int s = 0;
    for (int i = 0; i < 32; ++i) s += hist[base + i];
    tsum[tid] = s;
    __syncthreads();
    // Hillis-Steele inclusive scan over 256 strip sums
    for (int off = 1; off < 256; off <<= 1) {
        unsigned int v = tsum[tid];
        unsigned int add = (tid >= off) ? tsum[tid - off] : 0u;
        __syncthreads();
        tsum[tid] = v + add;
        __syncthreads();
    }
    unsigned int cum = (tid == 0) ? 0u : tsum[tid - 1];

    const unsigned int K0 = 26214u, K1v = 26215u, K2v = 235928u, K3v = 235929u;
    for (int i = 0; i < 32; ++i) {
        unsigned int h = hist[base + i];
        unsigned int nc = cum + h;
        if (h) {
            float edge = (float)(base + i);
            float invh = 1.0f / (float)h;
#define CHECK(KT, slot)                                                     \
            if (KT >= cum && KT < nc) {                                     \
                float r = (float)(KT - cum);                                \
                vals[slot] = (edge + (r + 0.5f) * invh) * (1.0f / BINS);    \
            }
            CHECK(K0, 0) CHECK(K1v, 1) CHECK(K2v, 2) CHECK(K3v, 3)
#undef CHECK
        }
        cum = nc;
    }
    __syncthreads();

    if (tid == 0) {
        // pos_lo = 0.1*(n-1) = 26214.3 -> frac .3 ; pos_hi = 235928.7 -> frac .7
        float lo = 0.7f * vals[0] + 0.3f * vals[1];
        float hi = 0.3f * vals[2] + 0.7f * vals[3];
        float rng = fmaxf(hi - lo, 0.01f);
        lo_inv[b * 2 + 0] = lo;
        lo_inv[b * 2 + 1] = 1.0f / rng;
    }
}

// ---------------- K3: normalize in place ----------------
__global__ __launch_bounds__(256) void k_norm(float* __restrict__ xm,
                                              const float* __restrict__ lo_inv) {
    const int i = blockIdx.x * 256 + threadIdx.x;       // float4 index
    const int b = i >> 16;                              // 65536 float4 / batch
    const float lo = lo_inv[b * 2 + 0];
    const float inv = lo_inv[b * 2 + 1];
    float4* P = (float4*)xm;
    float4 v = P[i];
    v.x = fminf(fmaxf((v.x - lo) * inv, 0.0f), 1.0f);
    v.y = fminf(fmaxf((v.y - lo) * inv, 0.0f), 1.0f);
    v.z = fminf(fmaxf((v.z - lo) * inv, 0.0f), 1.0f);
    v.w = fminf(fmaxf((v.w - lo) * inv, 0.0f), 1.0f);
    P[i] = v;
}

extern "C" void kernel_launch(void* const* d_in, const int* in_sizes, int n_in,
                              void* d_out, int out_size, void* d_ws, size_t ws_size,
                              hipStream_t stream) {
    const float* x = (const float*)d_in[0];
    float* out = (float*)d_out;

    float* lo_inv = (float*)d_ws;                       // 64*2 floats
    unsigned short* subhist = (unsigned short*)((char*)d_ws + 4096);
    size_t avail = ws_size > 4096 ? ws_size - 4096 : 0;

    int nb = 16;
    while (nb > 1 && (size_t)64 * nb * BINS * sizeof(unsigned short) > avail) nb >>= 1;
    const int chunk = PIX_PER_BATCH / nb;

    k_mean_hist<<<64 * nb, 256, 0, stream>>>(x, out, subhist, nb, chunk);
    k_quantile<<<64, 256, 0, stream>>>(subhist, lo_inv, nb);
    k_norm<<<(out_size / 4 + 255) / 256, 256, 0, stream>>>(out, lo_inv);
}

// Round 2
// 96.098 us; speedup vs baseline: 1.5327x; 1.5327x over previous
//
#include <hip/hip_runtime.h>

// Problem: x [64, 512, 512, 3] f32.  out = clip((mean_c(x) - q10)/max(q90-q10, .01), 0, 1)
// B=64, HW=262144 pixels/batch, 786432 floats/batch.

#define BINS 8192
#define PIX_PER_BATCH 262144
#define NB 16            // sub-blocks per batch in K1

// ---------------- K0: zero the global histogram region ----------------
__global__ __launch_bounds__(256) void k_zero(uint4* __restrict__ p) {
    p[blockIdx.x * 256 + threadIdx.x] = make_uint4(0u, 0u, 0u, 0u);
}

// ---------------- K1: fused channel-mean + histogram ----------------
// Each block handles one contiguous chunk of pixels of one batch.
// Writes xm to out (float4 coalesced); accumulates an LDS histogram and
// flushes it to the per-batch global u32 histogram via atomicAdd.
__global__ __launch_bounds__(256) void k_mean_hist(const float* __restrict__ x,
                                                   float* __restrict__ xm,
                                                   unsigned int* __restrict__ histg) {
    __shared__ unsigned int hist[BINS];
    const int tid = threadIdx.x;
    const int b = blockIdx.x / NB;
    const int c = blockIdx.x % NB;

    for (int i = tid; i < BINS; i += 256) hist[i] = 0;
    __syncthreads();

    const float4* __restrict__ X4 = (const float4*)x;
    float4* __restrict__ O4 = (float4*)xm;

    const int chunk = PIX_PER_BATCH / NB;             // 16384 pixels
    const int pix0 = b * PIX_PER_BATCH + c * chunk;   // multiple of 1024
    const int iters = chunk / 1024;                   // 256 threads x 4 pixels

    for (int it = 0; it < iters; ++it) {
        const int p = pix0 + it * 1024 + tid * 4;     // pixel index, %4==0
        const int f4 = (p * 3) >> 2;                  // float4 index
        float4 a = X4[f4 + 0];
        float4 d = X4[f4 + 1];
        float4 e = X4[f4 + 2];
        const float k3 = 1.0f / 3.0f;
        float s0 = (a.x + a.y + a.z) * k3;
        float s1 = (a.w + d.x + d.y) * k3;
        float s2 = (d.z + d.w + e.x) * k3;
        float s3 = (e.y + e.z + e.w) * k3;
        O4[p >> 2] = make_float4(s0, s1, s2, s3);
        int b0 = min(BINS - 1, max(0, (int)(s0 * (float)BINS)));
        int b1 = min(BINS - 1, max(0, (int)(s1 * (float)BINS)));
        int b2 = min(BINS - 1, max(0, (int)(s2 * (float)BINS)));
        int b3 = min(BINS - 1, max(0, (int)(s3 * (float)BINS)));
        atomicAdd(&hist[b0], 1u);
        atomicAdd(&hist[b1], 1u);
        atomicAdd(&hist[b2], 1u);
        atomicAdd(&hist[b3], 1u);
    }
    __syncthreads();

    unsigned int* dst = histg + (size_t)b * BINS;
    for (int i = tid; i < BINS; i += 256) {
        unsigned int v = hist[i];
        if (v) atomicAdd(&dst[i], v);   // device-scope: safe across XCDs
    }
}

// ---------------- K2: per-batch quantiles from histogram ----------------
// One block per batch. Coalesced uint4 load of the 8192-bin histogram into
// LDS, strip-sum + scan, locate order statistics {26214,26215,235928,235929}
// (q*(n-1) linear interp, n=262144), uniform within-bin estimate.
__global__ __launch_bounds__(256) void k_quantile(const unsigned int* __restrict__ histg,
                                                  float* __restrict__ lo_inv) {
    __shared__ unsigned int hist[BINS];
    __shared__ unsigned int tsum[256];
    __shared__ float vals[4];
    const int b = blockIdx.x;
    const int tid = threadIdx.x;

    const uint4* __restrict__ H4 = (const uint4*)(histg + (size_t)b * BINS);
    uint4* L4 = (uint4*)hist;
    for (int i = tid; i < BINS / 4; i += 256) L4[i] = H4[i];
    __syncthreads();

    // strip sums: thread t owns bins [t*32, t*32+32)
    const int base = tid * 32;
    unsigned int s = 0;
    for (int i = 0; i < 32; ++i) s += hist[base + i];
    tsum[tid] = s;
    __syncthreads();
    // Hillis-Steele inclusive scan over 256 strip sums
    for (int off = 1; off < 256; off <<= 1) {
        unsigned int v = tsum[tid];
        unsigned int add = (tid >= off) ? tsum[tid - off] : 0u;
        __syncthreads();
        tsum[tid] = v + add;
        __syncthreads();
    }
    unsigned int cum = (tid == 0) ? 0u : tsum[tid - 1];

    const unsigned int K0 = 26214u, K1v = 26215u, K2v = 235928u, K3v = 235929u;
    for (int i = 0; i < 32; ++i) {
        unsigned int h = hist[base + i];
        unsigned int nc = cum + h;
        if (h) {
            float edge = (float)(base + i);
            float invh = 1.0f / (float)h;
#define CHECK(KT, slot)                                                     \
            if (KT >= cum && KT < nc) {                                     \
                float r = (float)(KT - cum);                                \
                vals[slot] = (edge + (r + 0.5f) * invh) * (1.0f / BINS);    \
            }
            CHECK(K0, 0) CHECK(K1v, 1) CHECK(K2v, 2) CHECK(K3v, 3)
#undef CHECK
        }
        cum = nc;
    }
    __syncthreads();

    if (tid == 0) {
        // pos_lo = 0.1*(n-1) = 26214.3 -> frac .3 ; pos_hi = 235928.7 -> frac .7
        float lo = 0.7f * vals[0] + 0.3f * vals[1];
        float hi = 0.3f * vals[2] + 0.7f * vals[3];
        float rng = fmaxf(hi - lo, 0.01f);
        lo_inv[b * 2 + 0] = lo;
        lo_inv[b * 2 + 1] = 1.0f / rng;
    }
}

// ---------------- K3: normalize in place ----------------
__global__ __launch_bounds__(256) void k_norm(float* __restrict__ xm,
                                              const float* __restrict__ lo_inv) {
    const int i = blockIdx.x * 256 + threadIdx.x;       // float4 index
    const int b = i >> 16;                              // 65536 float4 / batch
    const float lo = lo_inv[b * 2 + 0];
    const float inv = lo_inv[b * 2 + 1];
    float4* P = (float4*)xm;
    float4 v = P[i];
    v.x = fminf(fmaxf((v.x - lo) * inv, 0.0f), 1.0f);
    v.y = fminf(fmaxf((v.y - lo) * inv, 0.0f), 1.0f);
    v.z = fminf(fmaxf((v.z - lo) * inv, 0.0f), 1.0f);
    v.w = fminf(fmaxf((v.w - lo) * inv, 0.0f), 1.0f);
    P[i] = v;
}

extern "C" void kernel_launch(void* const* d_in, const int* in_sizes, int n_in,
                              void* d_out, int out_size, void* d_ws, size_t ws_size,
                              hipStream_t stream) {
    const float* x = (const float*)d_in[0];
    float* out = (float*)d_out;

    float* lo_inv = (float*)d_ws;                                   // 64*2 floats
    unsigned int* histg = (unsigned int*)((char*)d_ws + 4096);      // 64*8192*4 = 2 MB

    // zero the 2 MB histogram region (ws is poisoned, never re-poisoned)
    k_zero<<<(64 * BINS / 4) / 256, 256, 0, stream>>>((uint4*)histg);
    k_mean_hist<<<64 * NB, 256, 0, stream>>>(x, out, histg);
    k_quantile<<<64, 256, 0, stream>>>(histg, lo_inv);
    k_norm<<<(out_size / 4 + 255) / 256, 256, 0, stream>>>(out, lo_inv);
}

// Round 4
// 95.715 us; speedup vs baseline: 1.5389x; 1.0040x over previous
//
#include <hip/hip_runtime.h>
#include <hip/hip_cooperative_groups.h>

namespace cg = cooperative_groups;

// Problem: x [64, 512, 512, 3] f32.  out = clip((mean_c(x) - q10)/max(q90-q10, .01), 0, 1)
// B=64, HW=262144 px/batch. Cooperative single-kernel: xm lives in VGPRs
// (128 px/thread as 64 packed-u16 regs). HBM: read x 201 MB + hist 4 MB + write 67 MB.
// LDS kept at ~17.4 KB so 2 blocks/CU co-residency passes under 64 KB accounting.

#define BINS 8192
#define PIXB 262144
#define NBLK 512
#define ITERS 32         // 32 iters x 1024 px = 32768 px/block

__global__ __launch_bounds__(256, 2) void k_fused(const float* __restrict__ x,
                                                  float* __restrict__ out,
                                                  unsigned int* __restrict__ histg,
                                                  float* __restrict__ lo_inv) {
    __shared__ unsigned int histp[BINS / 2];   // packed u16 pair per word, 16 KB
    __shared__ unsigned int tsum[256];
    __shared__ float vals[4];

    const int tid = threadIdx.x;
    const int b = blockIdx.x >> 3;
    const int c = blockIdx.x & 7;
    cg::grid_group grid = cg::this_grid();

    // ---- phase 0: zero global hist (disjoint 4 KB slices) + LDS hist ----
    {
        uint4* Z = (uint4*)(histg + blockIdx.x * 1024);   // 512*1024 = 64*8192
        Z[tid] = make_uint4(0u, 0u, 0u, 0u);
    }
    for (int i = tid; i < BINS / 2; i += 256) histp[i] = 0;
    grid.sync();

    // ---- phase 1: stream x, channel means -> u16 regs + packed LDS hist ----
    const float4* __restrict__ X4 = (const float4*)x;
    const int pix0 = b * PIXB + c * (PIXB / 8);
    unsigned int keep[2 * ITERS];             // 64 VGPRs: 128 px as packed u16
    const float k3 = 1.0f / 3.0f;
#pragma unroll
    for (int it = 0; it < ITERS; ++it) {
        const int p = pix0 + it * 1024 + tid * 4;
        const int f4 = (p * 3) >> 2;
        float4 a = X4[f4 + 0];
        float4 d = X4[f4 + 1];
        float4 e = X4[f4 + 2];
        float s0 = (a.x + a.y + a.z) * k3;
        float s1 = (a.w + d.x + d.y) * k3;
        float s2 = (d.z + d.w + e.x) * k3;
        float s3 = (e.y + e.z + e.w) * k3;
        unsigned int q0 = (unsigned int)(s0 * 65535.0f + 0.5f);   // < 65536 (x<1)
        unsigned int q1 = (unsigned int)(s1 * 65535.0f + 0.5f);
        unsigned int q2 = (unsigned int)(s2 * 65535.0f + 0.5f);
        unsigned int q3 = (unsigned int)(s3 * 65535.0f + 0.5f);
        keep[2 * it]     = q0 | (q1 << 16);
        keep[2 * it + 1] = q2 | (q3 << 16);
        // bin = q>>3 in [0,8192); packed: word bin>>1, half bin&1.
        // Max 32768 adds/block -> low half can never overflow into high.
        atomicAdd(&histp[q0 >> 4], 1u << (((q0 >> 3) & 1) * 16));
        atomicAdd(&histp[q1 >> 4], 1u << (((q1 >> 3) & 1) * 16));
        atomicAdd(&histp[q2 >> 4], 1u << (((q2 >> 3) & 1) * 16));
        atomicAdd(&histp[q3 >> 4], 1u << (((q3 >> 3) & 1) * 16));
    }
    __syncthreads();
    {
        unsigned int* dst = histg + (size_t)b * BINS;
        for (int i = tid; i < BINS / 2; i += 256) {
            unsigned int w = histp[i];
            unsigned int lo16 = w & 0xffffu, hi16 = w >> 16;
            if (lo16) atomicAdd(&dst[2 * i + 0], lo16);
            if (hi16) atomicAdd(&dst[2 * i + 1], hi16);
        }
    }
    grid.sync();

    // ---- phase 2: blocks 0..63 -> per-batch quantiles (hist in VGPRs) ----
    if (blockIdx.x < 64) {
        const int bb = blockIdx.x;
        const uint4* __restrict__ H4 = (const uint4*)(histg + (size_t)bb * BINS);
        uint4 hh[8];                          // bins [tid*32, tid*32+32)
#pragma unroll
        for (int j = 0; j < 8; ++j) hh[j] = H4[tid * 8 + j];
        unsigned int s = 0;
#pragma unroll
        for (int j = 0; j < 8; ++j) s += hh[j].x + hh[j].y + hh[j].z + hh[j].w;
        tsum[tid] = s;
        __syncthreads();
        for (int off = 1; off < 256; off <<= 1) {   // Hillis-Steele inclusive
            unsigned int v = tsum[tid];
            unsigned int add = (tid >= off) ? tsum[tid - off] : 0u;
            __syncthreads();
            tsum[tid] = v + add;
            __syncthreads();
        }
        unsigned int cum = (tid == 0) ? 0u : tsum[tid - 1];

        // order stats: q*(n-1), n=262144 -> 26214.3 / 235928.7
        const unsigned int T0 = 26214u, T1 = 26215u, T2 = 235928u, T3 = 235929u;
        const int base = tid * 32;
#pragma unroll
        for (int j = 0; j < 8; ++j) {
            unsigned int e4[4] = {hh[j].x, hh[j].y, hh[j].z, hh[j].w};
#pragma unroll
            for (int q = 0; q < 4; ++q) {
                unsigned int h = e4[q];
                unsigned int nc = cum + h;
                if (h) {
                    float edge = (float)(base + 4 * j + q);
                    float invh = 1.0f / (float)h;
#define CHECK(KT, slot)                                                     \
                    if (KT >= cum && KT < nc) {                             \
                        float r = (float)(KT - cum);                        \
                        vals[slot] = (edge + (r + 0.5f) * invh) * (1.0f / BINS);\
                    }
                    CHECK(T0, 0) CHECK(T1, 1) CHECK(T2, 2) CHECK(T3, 3)
#undef CHECK
                }
                cum = nc;
            }
        }
        __syncthreads();
        if (tid == 0) {
            float lo = 0.7f * vals[0] + 0.3f * vals[1];
            float hi = 0.3f * vals[2] + 0.7f * vals[3];
            float rng = fmaxf(hi - lo, 0.01f);
            lo_inv[bb * 2 + 0] = lo;
            lo_inv[bb * 2 + 1] = 1.0f / rng;
        }
    }
    grid.sync();

    // ---- phase 3: normalize register-held means, write out ----
    const float lo = lo_inv[b * 2 + 0];
    const float inv = lo_inv[b * 2 + 1];
    float4* __restrict__ O4 = (float4*)out;
    const float uq = 1.0f / 65535.0f;
#pragma unroll
    for (int it = 0; it < ITERS; ++it) {
        const int p = pix0 + it * 1024 + tid * 4;
        unsigned int u01 = keep[2 * it];
        unsigned int u23 = keep[2 * it + 1];
        float4 v;
        v.x = fminf(fmaxf(((float)(u01 & 0xffffu) * uq - lo) * inv, 0.0f), 1.0f);
        v.y = fminf(fmaxf(((float)(u01 >> 16)     * uq - lo) * inv, 0.0f), 1.0f);
        v.z = fminf(fmaxf(((float)(u23 & 0xffffu) * uq - lo) * inv, 0.0f), 1.0f);
        v.w = fminf(fmaxf(((float)(u23 >> 16)     * uq - lo) * inv, 0.0f), 1.0f);
        O4[p >> 2] = v;
    }
}

// ================= fallback path (R2, known-good 96 us) =================
#define NB 16
__global__ __launch_bounds__(256) void k_zero(uint4* __restrict__ p) {
    p[blockIdx.x * 256 + threadIdx.x] = make_uint4(0u, 0u, 0u, 0u);
}

__global__ __launch_bounds__(256) void k_mean_hist(const float* __restrict__ x,
                                                   float* __restrict__ xm,
                                                   unsigned int* __restrict__ histg) {
    __shared__ unsigned int hist[BINS];
    const int tid = threadIdx.x;
    const int b = blockIdx.x / NB;
    const int c = blockIdx.x % NB;
    for (int i = tid; i < BINS; i += 256) hist[i] = 0;
    __syncthreads();
    const float4* __restrict__ X4 = (const float4*)x;
    float4* __restrict__ O4 = (float4*)xm;
    const int chunk = PIXB / NB;
    const int pix0 = b * PIXB + c * chunk;
    const int iters = chunk / 1024;
    for (int it = 0; it < iters; ++it) {
        const int p = pix0 + it * 1024 + tid * 4;
        const int f4 = (p * 3) >> 2;
        float4 a = X4[f4 + 0];
        float4 d = X4[f4 + 1];
        float4 e = X4[f4 + 2];
        const float k3 = 1.0f / 3.0f;
        float s0 = (a.x + a.y + a.z) * k3;
        float s1 = (a.w + d.x + d.y) * k3;
        float s2 = (d.z + d.w + e.x) * k3;
        float s3 = (e.y + e.z + e.w) * k3;
        O4[p >> 2] = make_float4(s0, s1, s2, s3);
        atomicAdd(&hist[min(BINS - 1, max(0, (int)(s0 * (float)BINS)))], 1u);
        atomicAdd(&hist[min(BINS - 1, max(0, (int)(s1 * (float)BINS)))], 1u);
        atomicAdd(&hist[min(BINS - 1, max(0, (int)(s2 * (float)BINS)))], 1u);
        atomicAdd(&hist[min(BINS - 1, max(0, (int)(s3 * (float)BINS)))], 1u);
    }
    __syncthreads();
    unsigned int* dst = histg + (size_t)b * BINS;
    for (int i = tid; i < BINS; i += 256) {
        unsigned int v = hist[i];
        if (v) atomicAdd(&dst[i], v);
    }
}

__global__ __launch_bounds__(256) void k_quantile(const unsigned int* __restrict__ histg,
                                                  float* __restrict__ lo_inv) {
    __shared__ unsigned int hist[BINS];
    __shared__ unsigned int tsum[256];
    __shared__ float vals[4];
    const int b = blockIdx.x;
    const int tid = threadIdx.x;
    const uint4* __restrict__ H4 = (const uint4*)(histg + (size_t)b * BINS);
    uint4* L4 = (uint4*)hist;
    for (int i = tid; i < BINS / 4; i += 256) L4[i] = H4[i];
    __syncthreads();
    const int base = tid * 32;
    unsigned int s = 0;
    for (int i = 0; i < 32; ++i) s += hist[base + i];
    tsum[tid] = s;
    __syncthreads();
    for (int off = 1; off < 256; off <<= 1) {
        unsigned int v = tsum[tid];
        unsigned int add = (tid >= off) ? tsum[tid - off] : 0u;
        __syncthreads();
        tsum[tid] = v + add;
        __syncthreads();
    }
    unsigned int cum = (tid == 0) ? 0u : tsum[tid - 1];
    const unsigned int T0 = 26214u, T1 = 26215u, T2 = 235928u, T3 = 235929u;
    for (int i = 0; i < 32; ++i) {
        unsigned int h = hist[base + i];
        unsigned int nc = cum + h;
        if (h) {
            float edge = (float)(base + i);
            float invh = 1.0f / (float)h;
#define CHECK(KT, slot)                                                     \
            if (KT >= cum && KT < nc) {                                     \
                float r = (float)(KT - cum);                                \
                vals[slot] = (edge + (r + 0.5f) * invh) * (1.0f / BINS);    \
            }
            CHECK(T0, 0) CHECK(T1, 1) CHECK(T2, 2) CHECK(T3, 3)
#undef CHECK
        }
        cum = nc;
    }
    __syncthreads();
    if (tid == 0) {
        float lo = 0.7f * vals[0] + 0.3f * vals[1];
        float hi = 0.3f * vals[2] + 0.7f * vals[3];
        float rng = fmaxf(hi - lo, 0.01f);
        lo_inv[b * 2 + 0] = lo;
        lo_inv[b * 2 + 1] = 1.0f / rng;
    }
}

__global__ __launch_bounds__(256) void k_norm(float* __restrict__ xm,
                                              const float* __restrict__ lo_inv) {
    const int i = blockIdx.x * 256 + threadIdx.x;
    const int b = i >> 16;
    const float lo = lo_inv[b * 2 + 0];
    const float inv = lo_inv[b * 2 + 1];
    float4* P = (float4*)xm;
    float4 v = P[i];
    v.x = fminf(fmaxf((v.x - lo) * inv, 0.0f), 1.0f);
    v.y = fminf(fmaxf((v.y - lo) * inv, 0.0f), 1.0f);
    v.z = fminf(fmaxf((v.z - lo) * inv, 0.0f), 1.0f);
    v.w = fminf(fmaxf((v.w - lo) * inv, 0.0f), 1.0f);
    P[i] = v;
}

extern "C" void kernel_launch(void* const* d_in, const int* in_sizes, int n_in,
                              void* d_out, int out_size, void* d_ws, size_t ws_size,
                              hipStream_t stream) {
    const float* x = (const float*)d_in[0];
    float* out = (float*)d_out;
    float* lo_inv = (float*)d_ws;                                   // 64*2 floats
    unsigned int* histg = (unsigned int*)((char*)d_ws + 4096);      // 2 MB

    // Capture-safe occupancy query: need 2 blocks/CU so 512 blocks co-reside.
    int occ = 0;
    hipError_t qe = hipOccupancyMaxActiveBlocksPerMultiprocessor(&occ, k_fused, 256, 0);
    bool coop_ok = (qe == hipSuccess) && (occ >= 2);

    if (coop_ok) {
        void* args[] = {(void*)&x, (void*)&out, (void*)&histg, (void*)&lo_inv};
        hipError_t rc = hipLaunchCooperativeKernel((void*)k_fused, dim3(NBLK),
                                                   dim3(256), args, 0, stream);
        if (rc == hipSuccess) return;
    }
    // fallback: known-good 4-kernel path
    k_zero<<<(64 * BINS / 4) / 256, 256, 0, stream>>>((uint4*)histg);
    k_mean_hist<<<64 * NB, 256, 0, stream>>>(x, out, histg);
    k_quantile<<<64, 256, 0, stream>>>(histg, lo_inv);
    k_norm<<<(out_size / 4 + 255) / 256, 256, 0, stream>>>(out, lo_inv);
}